// Round 4
// baseline (1812.110 us; speedup 1.0000x reference)
//
#include <hip/hip_runtime.h>
#include <math.h>

#define SB 1024
#define NS 64
#define BT 256
#define HID 64
#define HEAD 128

// d_ws (floats): [0..4095] G = W3*W3^T (64x64), [4096..4159] g = W3*b3
#define WS_G 0
#define WS_g 4096

// load 16 consecutive LDS floats into registers via 4x ds_read_b128
#define LOAD16(DST, SRC) do {                                           \
    const float4* _s4 = (const float4*)(SRC);                           \
    float4 _a = _s4[0], _b = _s4[1], _c = _s4[2], _d = _s4[3];          \
    (DST)[0]=_a.x;  (DST)[1]=_a.y;  (DST)[2]=_a.z;  (DST)[3]=_a.w;      \
    (DST)[4]=_b.x;  (DST)[5]=_b.y;  (DST)[6]=_b.z;  (DST)[7]=_b.w;      \
    (DST)[8]=_c.x;  (DST)[9]=_c.y;  (DST)[10]=_c.z; (DST)[11]=_c.w;     \
    (DST)[12]=_d.x; (DST)[13]=_d.y; (DST)[14]=_d.z; (DST)[15]=_d.w;     \
} while (0)

// 4q x 16i tile FMA: ACC[qq][tt] += XQ[qq] * W[tt]
#define FMA_TILE(ACC, XQ, W) do {                                       \
    _Pragma("unroll")                                                   \
    for (int _qq = 0; _qq < 4; ++_qq) {                                 \
        float _x = (XQ)[_qq];                                           \
        _Pragma("unroll")                                               \
        for (int _tt = 0; _tt < 16; ++_tt)                              \
            (ACC)[_qq][_tt] = fmaf(_x, (W)[_tt], (ACC)[_qq][_tt]);      \
    }                                                                   \
} while (0)

// 16 accumulators ACC[0..15] += V * WPTR[0..15]  (key phase, R2-style)
#define FMA16(ACC, WPTR, V) do {                                        \
    float _w[16]; LOAD16(_w, WPTR);                                     \
    _Pragma("unroll")                                                   \
    for (int _t = 0; _t < 16; ++_t)                                     \
        (ACC)[_t] = fmaf((V), _w[_t], (ACC)[_t]);                       \
} while (0)

__device__ __forceinline__ void load_pose(const float* __restrict__ p,
                                          float& lx, float& ly, float& lz,
                                          float& dx, float& dy, float& dz) {
    float2 r0 = *(const float2*)(p + 2);
    float2 r1 = *(const float2*)(p + 6);
    float2 r2 = *(const float2*)(p + 10);
    dx = r0.x; lx = r0.y;
    dy = r1.x; ly = r1.y;
    dz = r2.x; lz = r2.y;
}

// x[42] = [loc3 | sin/cos interleaved, freqs 1.5*2^i | dir3]
__device__ __forceinline__ void pe_compute(float* x, float lx, float ly, float lz,
                                           float dx, float dy, float dz) {
    x[0] = lx; x[1] = ly; x[2] = lz;
    #pragma unroll
    for (int c = 0; c < 3; ++c) {
        float lc = (c == 0) ? lx : ((c == 1) ? ly : lz);
        float sv, cv;
        __sincosf(1.5f * lc, &sv, &cv);
        #pragma unroll
        for (int i = 0; i < 6; ++i) {
            x[3 + 6 * i + c] = sv;
            x[6 + 6 * i + c] = cv;
            float ns = 2.f * sv * cv, nc = cv * cv - sv * sv;
            sv = ns; cv = nc;
        }
    }
    x[39] = dx; x[40] = dy; x[41] = dz;
}

// ---------------- kernel 1: precompute G = W3 W3^T, g = W3 b3 ----------------
__global__ __launch_bounds__(256) void precompute_kernel(
    const float* __restrict__ W3, const float* __restrict__ b3, float* __restrict__ ws)
{
    __shared__ float W3t[HEAD][HID];   // W3t[d][j] = W3[j*128+d]
    const int tid = threadIdx.x;
    for (int i = tid; i < HID * HEAD / 4; i += 256) {
        float4 v = ((const float4*)W3)[i];
        int j = i >> 5, d0 = (i & 31) * 4;
        W3t[d0 + 0][j] = v.x;
        W3t[d0 + 1][j] = v.y;
        W3t[d0 + 2][j] = v.z;
        W3t[d0 + 3][j] = v.w;
    }
    __syncthreads();

    const int k = tid & 63, rr = tid >> 6;
    const int r0 = blockIdx.x * 8 + rr;       // rows r0 and r0+4
    float acc0 = 0.f, acc1 = 0.f;
    for (int d = 0; d < HEAD; ++d) {
        float wk = W3t[d][k];
        acc0 = fmaf(W3t[d][r0], wk, acc0);
        acc1 = fmaf(W3t[d][r0 + 4], wk, acc1);
    }
    ws[WS_G + r0 * 64 + k]       = acc0;
    ws[WS_G + (r0 + 4) * 64 + k] = acc1;

    if (blockIdx.x == 0 && tid < 64) {
        float g = 0.f;
        for (int d = 0; d < HEAD; ++d) g = fmaf(W3t[d][tid], b3[d], g);
        ws[WS_g + tid] = g;
    }
}

// ---------------- kernel 2: main fused kernel ----------------
__global__ __launch_bounds__(256, 2) void cam_weighter_kernel(
    const float* __restrict__ input_poses,   // (SB,NS,4,4)
    const float* __restrict__ target_poses,  // (SB,BT,4,4)
    const float* __restrict__ W1, const float* __restrict__ b1,
    const float* __restrict__ W2, const float* __restrict__ b2,
    const float* __restrict__ ws,            // G | g
    float* __restrict__ out)                 // (SB,NS,BT)
{
    __shared__ __align__(16) float W1l[42 * 64];    // 10.5 KB, resident
    __shared__ __align__(16) float W2l[64 * 64];    // 16 KB, resident
    __shared__ __align__(16) float zkl[64 * 64];    // 16 KB: h1_k -> zk
    __shared__ __align__(16) float bufB[64 * 64];   // 16 KB: h2_k -> query chunks
    __shared__ __align__(16) float Gl[64 * 64];     // 16 KB, key phase only
    __shared__ __align__(16) float b1l[64], b2l[64], gl_s[64], ckl[64];

    const int tid = threadIdx.x;
    const int s   = blockIdx.x;

    // ---------- stage weights ----------
    for (int i = tid; i < 672; i += 256)  ((float4*)W1l)[i] = ((const float4*)W1)[i];
    for (int i = tid; i < 1024; i += 256) ((float4*)W2l)[i] = ((const float4*)W2)[i];
    for (int i = tid; i < 1024; i += 256) ((float4*)Gl)[i]  = ((const float4*)(ws + WS_G))[i];
    if (tid < 16)       ((float4*)b1l)[tid]      = ((const float4*)b1)[tid];
    else if (tid < 32)  ((float4*)b2l)[tid - 16] = ((const float4*)b2)[tid - 16];
    else if (tid < 48)  ((float4*)gl_s)[tid - 32] = ((const float4*)(ws + WS_g))[tid - 32];
    __syncthreads();

    // ================= keys (R2-style: thread = (k, 16-wide output slice)) =================
    {
        const int k = tid & 63;
        const int i0 = (tid >> 6) * 16;

        float lx, ly, lz, dx, dy, dz;
        load_pose(&input_poses[((size_t)s * NS + k) * 16], lx, ly, lz, dx, dy, dz);
        float x[42];
        pe_compute(x, lx, ly, lz, dx, dy, dz);

        float a[16];
        #pragma unroll
        for (int t = 0; t < 16; ++t) a[t] = b1l[i0 + t];
        #pragma unroll
        for (int j = 0; j < 42; ++j) FMA16(a, &W1l[j * 64 + i0], x[j]);
        #pragma unroll
        for (int t = 0; t < 16; ++t) zkl[(i0 + t) * 64 + k] = fmaxf(a[t], 0.f);  // h1_k
        __syncthreads();

        #pragma unroll
        for (int t = 0; t < 16; ++t) a[t] = b2l[i0 + t];
        #pragma unroll 8
        for (int j = 0; j < HID; ++j) {
            float hv = zkl[j * 64 + k];
            FMA16(a, &W2l[j * 64 + i0], hv);
        }
        #pragma unroll
        for (int t = 0; t < 16; ++t) bufB[(i0 + t) * 64 + k] = fmaxf(a[t], 0.f);  // h2_k
        __syncthreads();

        float ck = 0.f;
        #pragma unroll
        for (int t = 0; t < 16; ++t) a[t] = 0.f;
        #pragma unroll 8
        for (int j = 0; j < HID; ++j) {
            float hv = bufB[j * 64 + k];
            FMA16(a, &Gl[j * 64 + i0], hv);
            ck = fmaf(hv, gl_s[j], ck);
        }
        __syncthreads();                       // all h1 reads of zkl done; safe to overwrite
        #pragma unroll
        for (int t = 0; t < 16; ++t) zkl[(i0 + t) * 64 + k] = a[t];   // zk
        if (tid < 64) ckl[k] = ck;
        __syncthreads();
    }

    // ================= queries (register-tiled 4q x 16) =================
    {
        const int qt = tid >> 2;        // q-group: q = qt*4 + qq
        const int st = tid & 3;         // sub-tile: i0/k0 = st*16
        const int i0 = st * 16;
        const int qb = qt << 2;

        float lx, ly, lz, dx, dy, dz;
        load_pose(&target_poses[((size_t)s * BT + tid) * 16], lx, ly, lz, dx, dy, dz);
        float x[42];
        pe_compute(x, lx, ly, lz, dx, dy, dz);

        // ---- layer 1 (42 -> 64), x redistributed via LDS chunks ----
        float acc[4][16];
        {
            float bv[16]; LOAD16(bv, &b1l[i0]);
            #pragma unroll
            for (int qq = 0; qq < 4; ++qq)
                #pragma unroll
                for (int tt = 0; tt < 16; ++tt) acc[qq][tt] = bv[tt];
        }
        #pragma unroll
        for (int r = 0; r < 3; ++r) {
            const int j0 = 16 * r;
            const int nj = (r == 2) ? 10 : 16;
            #pragma unroll
            for (int jj = 0; jj < 16; ++jj)
                if (jj < nj) bufB[jj * 256 + tid] = x[j0 + jj];
            __syncthreads();
            #pragma unroll
            for (int jj = 0; jj < 16; ++jj) {
                if (jj < nj) {
                    float4 xv = *(const float4*)&bufB[jj * 256 + qb];
                    float xq[4] = {xv.x, xv.y, xv.z, xv.w};
                    float w[16]; LOAD16(w, &W1l[(j0 + jj) * 64 + i0]);
                    FMA_TILE(acc, xq, w);
                }
            }
            __syncthreads();
        }
        #pragma unroll
        for (int qq = 0; qq < 4; ++qq)
            #pragma unroll
            for (int tt = 0; tt < 16; ++tt) acc[qq][tt] = fmaxf(acc[qq][tt], 0.f);

        // ---- layer 2 (64 -> 64), h1 redistributed via LDS chunks ----
        float acc2[4][16];
        {
            float bv[16]; LOAD16(bv, &b2l[i0]);
            #pragma unroll
            for (int qq = 0; qq < 4; ++qq)
                #pragma unroll
                for (int tt = 0; tt < 16; ++tt) acc2[qq][tt] = bv[tt];
        }
        #pragma unroll
        for (int ic = 0; ic < 4; ++ic) {
            if (st == ic) {
                #pragma unroll
                for (int tt = 0; tt < 16; ++tt)
                    *(float4*)&bufB[tt * 256 + qb] =
                        make_float4(acc[0][tt], acc[1][tt], acc[2][tt], acc[3][tt]);
            }
            __syncthreads();
            #pragma unroll
            for (int jj = 0; jj < 16; ++jj) {
                float4 hv = *(const float4*)&bufB[jj * 256 + qb];
                float hq[4] = {hv.x, hv.y, hv.z, hv.w};
                float w[16]; LOAD16(w, &W2l[(ic * 16 + jj) * 64 + i0]);
                FMA_TILE(acc2, hq, w);
            }
            __syncthreads();
        }
        #pragma unroll
        for (int qq = 0; qq < 4; ++qq)
            #pragma unroll
            for (int tt = 0; tt < 16; ++tt) acc2[qq][tt] = fmaxf(acc2[qq][tt], 0.f);

        // ---- scores (4q x 16k per thread), h2 redistributed via LDS chunks ----
        float sc[4][16];
        {
            float cv[16]; LOAD16(cv, &ckl[i0]);
            #pragma unroll
            for (int qq = 0; qq < 4; ++qq)
                #pragma unroll
                for (int tt = 0; tt < 16; ++tt) sc[qq][tt] = cv[tt];
        }
        #pragma unroll
        for (int ic = 0; ic < 4; ++ic) {
            if (st == ic) {
                #pragma unroll
                for (int tt = 0; tt < 16; ++tt)
                    *(float4*)&bufB[tt * 256 + qb] =
                        make_float4(acc2[0][tt], acc2[1][tt], acc2[2][tt], acc2[3][tt]);
            }
            __syncthreads();
            #pragma unroll
            for (int jj = 0; jj < 16; ++jj) {
                float4 hv = *(const float4*)&bufB[jj * 256 + qb];
                float hq[4] = {hv.x, hv.y, hv.z, hv.w};
                float zr[16]; LOAD16(zr, &zkl[(ic * 16 + jj) * 64 + i0]);
                FMA_TILE(sc, hq, zr);
            }
            __syncthreads();
        }

        // ---- softmax over 64 k, split across the 4 lanes of a q-group ----
        const float scale = 0.08838834764831845f;   // 1/sqrt(128)
        float inv[4];
        #pragma unroll
        for (int qq = 0; qq < 4; ++qq) {
            float m = sc[qq][0];
            #pragma unroll
            for (int tt = 1; tt < 16; ++tt) m = fmaxf(m, sc[qq][tt]);
            m = fmaxf(m, __shfl_xor(m, 1));
            m = fmaxf(m, __shfl_xor(m, 2));
            float sum = 0.f;
            #pragma unroll
            for (int tt = 0; tt < 16; ++tt) {
                sc[qq][tt] = __expf((sc[qq][tt] - m) * scale);
                sum += sc[qq][tt];
            }
            sum += __shfl_xor(sum, 1);
            sum += __shfl_xor(sum, 2);
            inv[qq] = 1.f / sum;
        }

        // ---- transposed store: out[s][k][q], float4 across q ----
        float* obase = out + (size_t)s * NS * BT;
        #pragma unroll
        for (int tt = 0; tt < 16; ++tt) {
            float4 v = make_float4(sc[0][tt] * inv[0], sc[1][tt] * inv[1],
                                   sc[2][tt] * inv[2], sc[3][tt] * inv[3]);
            *(float4*)&obase[(size_t)(i0 + tt) * BT + qb] = v;
        }
    }
}

extern "C" void kernel_launch(void* const* d_in, const int* in_sizes, int n_in,
                              void* d_out, int out_size, void* d_ws, size_t ws_size,
                              hipStream_t stream) {
    const float* input_poses  = (const float*)d_in[0];
    const float* target_poses = (const float*)d_in[1];
    const float* W1 = (const float*)d_in[2];
    const float* b1 = (const float*)d_in[3];
    const float* W2 = (const float*)d_in[4];
    const float* b2 = (const float*)d_in[5];
    const float* W3 = (const float*)d_in[6];
    const float* b3 = (const float*)d_in[7];
    float* out = (float*)d_out;
    float* ws  = (float*)d_ws;   // needs 4160 floats

    precompute_kernel<<<dim3(8), dim3(256), 0, stream>>>(W3, b3, ws);
    cam_weighter_kernel<<<dim3(SB), dim3(256), 0, stream>>>(
        input_poses, target_poses, W1, b1, W2, b2, ws, out);
}

// Round 5
// 96.414 us; speedup vs baseline: 18.7950x; 18.7950x over previous
//
#include <hip/hip_runtime.h>
#include <math.h>

typedef __attribute__((ext_vector_type(8))) short short8;
typedef __attribute__((ext_vector_type(4))) float f32x4;

#define SCALE 0.08838834764831845f   // 1/sqrt(128)

// d_ws byte offsets (16640 B total, well under proven-safe 33 KB)
#define WS_G 0        // G planes: hi [64][64]bf16 (8192 B), lo (+8192)
#define WS_g 16384    // g = W3 b3, 64 f32

// LDS byte offsets (total exactly 81920 B -> 2 blocks/CU)
#define L_W1T 0       // [64 i][64 j] bf16 hi, lo at +8192 (cols 42..63 zero)
#define L_W2T 16384
#define L_G   32768   // G planes; overwritten by ZkT after barrier 1
#define L_XY  49152   // per-wave X/Y tile planes: wave w at +w*8192
#define PLANE 8192    // lo-offset for big [64]-row planes
#define TPLANE 2048   // lo-offset for [16]-row tile planes

__device__ __forceinline__ unsigned int f2bf(float f) {
    unsigned int u = __float_as_uint(f);
    return (u + 0x7fffu + ((u >> 16) & 1u)) >> 16;   // RNE to bf16 bits
}
__device__ __forceinline__ float bf2f(short b) {
    return __uint_as_float(((unsigned int)(unsigned short)b) << 16);
}
__device__ __forceinline__ int lds_addr(int row, int cb) {   // cb: byte within 128B row
    return (row * 128 + cb) ^ ((row & 7) << 4);              // XOR swizzle, slot-granular
}
__device__ __forceinline__ f32x4 mk4(float v) { f32x4 r = {v, v, v, v}; return r; }

// pack 8 fp32 -> bf16 hi+lo planes, one 16B chunk each
__device__ __forceinline__ void write8(char* hi, char* lo, int byte, const float* v) {
    unsigned int h[4], l[4];
#pragma unroll
    for (int i = 0; i < 4; ++i) {
        float a = v[2 * i], b = v[2 * i + 1];
        unsigned int ha = f2bf(a), hb = f2bf(b);
        h[i] = ha | (hb << 16);
        l[i] = f2bf(a - __uint_as_float(ha << 16)) |
               (f2bf(b - __uint_as_float(hb << 16)) << 16);
    }
    *(uint4*)(hi + byte) = make_uint4(h[0], h[1], h[2], h[3]);
    *(uint4*)(lo + byte) = make_uint4(l[0], l[1], l[2], l[3]);
}

// MFMA fragment: row = rowbase + (lane&15), 8 contiguous k at (lane>>4)*8 + ks*32
__device__ __forceinline__ short8 frag(const char* plane, int rowbase, int ks, int lane) {
    int r = rowbase + (lane & 15);
    int byte = lds_addr(r, ks * 64 + ((lane >> 4) << 4));
    return *(const short8*)(plane + byte);
}

// C += A*B over K=64 (2 ksteps) with hi/lo split (hh + hl + lh), N=64 (4 n-tiles)
__device__ __forceinline__ void gemm16(const char* A, int Alo, const char* B, int Blo,
                                       f32x4* acc, int lane) {
    short8 Ah0 = frag(A, 0, 0, lane), Ah1 = frag(A, 0, 1, lane);
    short8 Al0 = frag(A + Alo, 0, 0, lane), Al1 = frag(A + Alo, 0, 1, lane);
#pragma unroll
    for (int nt = 0; nt < 4; ++nt) {
        short8 bh0 = frag(B, nt * 16, 0, lane);
        short8 bl0 = frag(B + Blo, nt * 16, 0, lane);
        short8 bh1 = frag(B, nt * 16, 1, lane);
        short8 bl1 = frag(B + Blo, nt * 16, 1, lane);
        f32x4 a = acc[nt];
        a = __builtin_amdgcn_mfma_f32_16x16x32_bf16(Ah0, bh0, a, 0, 0, 0);
        a = __builtin_amdgcn_mfma_f32_16x16x32_bf16(Ah0, bl0, a, 0, 0, 0);
        a = __builtin_amdgcn_mfma_f32_16x16x32_bf16(Al0, bh0, a, 0, 0, 0);
        a = __builtin_amdgcn_mfma_f32_16x16x32_bf16(Ah1, bh1, a, 0, 0, 0);
        a = __builtin_amdgcn_mfma_f32_16x16x32_bf16(Ah1, bl1, a, 0, 0, 0);
        a = __builtin_amdgcn_mfma_f32_16x16x32_bf16(Al1, bh1, a, 0, 0, 0);
        acc[nt] = a;
    }
}

// C tile (relu optional) -> hi/lo planes.  C layout: col=lane&15(+16nt), row=(lane>>4)*4+r
__device__ __forceinline__ void store_c(char* hi, char* lo, const f32x4* acc,
                                        int rowbase, int lane, bool relu) {
#pragma unroll
    for (int nt = 0; nt < 4; ++nt) {
#pragma unroll
        for (int r = 0; r < 4; ++r) {
            float v = acc[nt][r];
            if (relu) v = fmaxf(v, 0.f);
            int row = rowbase + ((lane >> 4) << 2) + r;
            int byte = lds_addr(row, ((lane & 15) + nt * 16) * 2);
            unsigned int hb = f2bf(v);
            *(unsigned short*)(hi + byte) = (unsigned short)hb;
            *(unsigned short*)(lo + byte) =
                (unsigned short)f2bf(v - __uint_as_float(hb << 16));
        }
    }
}

// PE features: [loc3 | sin/cos interleaved x6 freqs (1.5*2^i) | dir3 | 6 zeros]
__device__ __forceinline__ void pe48(float* x, const float* __restrict__ pose) {
    float2 r0 = *(const float2*)(pose + 2);
    float2 r1 = *(const float2*)(pose + 6);
    float2 r2 = *(const float2*)(pose + 10);
    float lx = r0.y, ly = r1.y, lz = r2.y;
    x[0] = lx; x[1] = ly; x[2] = lz;
#pragma unroll
    for (int c = 0; c < 3; ++c) {
        float lc = (c == 0) ? lx : (c == 1) ? ly : lz;
        float sv, cv;
        __sincosf(1.5f * lc, &sv, &cv);
#pragma unroll
        for (int i = 0; i < 6; ++i) {
            x[3 + 6 * i + c] = sv;
            x[6 + 6 * i + c] = cv;
            float ns = 2.f * sv * cv, nc = cv * cv - sv * sv;
            sv = ns; cv = nc;
        }
    }
    x[39] = r0.x; x[40] = r1.x; x[41] = r2.x;
    x[42] = x[43] = x[44] = x[45] = x[46] = x[47] = 0.f;
}

// lane (row=lane&15) writes its 16-col quarter (qt=lane>>4) of the A tile
__device__ __forceinline__ void writeA(char* Xp, const float* x, int lane) {
    int row = lane & 15, qt = lane >> 4;
    char* hi = Xp;
    char* lo = Xp + TPLANE;
    if (qt == 0) {
        write8(hi, lo, lds_addr(row, 0), &x[0]);
        write8(hi, lo, lds_addr(row, 16), &x[8]);
    } else if (qt == 1) {
        write8(hi, lo, lds_addr(row, 32), &x[16]);
        write8(hi, lo, lds_addr(row, 48), &x[24]);
    } else if (qt == 2) {
        write8(hi, lo, lds_addr(row, 64), &x[32]);
        write8(hi, lo, lds_addr(row, 80), &x[40]);
    } else {
        uint4 z = make_uint4(0, 0, 0, 0);
        *(uint4*)(hi + lds_addr(row, 96)) = z;
        *(uint4*)(hi + lds_addr(row, 112)) = z;
        *(uint4*)(lo + lds_addr(row, 96)) = z;
        *(uint4*)(lo + lds_addr(row, 112)) = z;
    }
}

// ---------------- kernel 1: G = W3 W3^T (bf16 hi/lo planes), g = W3 b3 ----------------
__global__ __launch_bounds__(256) void precompute_kernel(
    const float* __restrict__ W3, const float* __restrict__ b3, char* __restrict__ ws)
{
    __shared__ float W3t[128][64];   // W3t[d][j] = W3[j*128+d]
    const int tid = threadIdx.x;
    for (int e = tid; e < 8192; e += 256) W3t[e & 127][e >> 7] = W3[e];
    __syncthreads();

    unsigned short* gh = (unsigned short*)(ws + WS_G);
    unsigned short* gl = gh + 4096;
    for (int idx = tid; idx < 4096; idx += 256) {
        int r = idx >> 6, k = idx & 63;
        float a = 0.f;
        for (int d = 0; d < 128; ++d) a = fmaf(W3t[d][r], W3t[d][k], a);
        unsigned int h = f2bf(a);
        gh[idx] = (unsigned short)h;
        gl[idx] = (unsigned short)f2bf(a - __uint_as_float(h << 16));
    }
    if (tid < 64) {
        float a = 0.f;
        for (int d = 0; d < 128; ++d) a = fmaf(W3t[d][tid], b3[d], a);
        ((float*)(ws + WS_g))[tid] = a;
    }
}

// ---------------- kernel 2: fused MFMA kernel, 1 scene/block ----------------
__global__ __launch_bounds__(256, 2) void cam_mfma_kernel(
    const float* __restrict__ input_poses, const float* __restrict__ target_poses,
    const float* __restrict__ W1, const float* __restrict__ b1,
    const float* __restrict__ W2, const float* __restrict__ b2,
    const char* __restrict__ ws, float* __restrict__ out)
{
    __shared__ __align__(16) char smem[81920];
    const int tid = threadIdx.x, lane = tid & 63, w = tid >> 6;
    const int s = blockIdx.x;

    // ---- stage W1T/W2T (split from global, swizzled) ----
    for (int idx = tid; idx < 4096; idx += 256) {
        int i = idx & 63, j = idx >> 6;               // coalesced over i
        int byte = lds_addr(i, j * 2);                // plane [i][j]
        float v1 = (j < 42) ? W1[j * 64 + i] : 0.f;
        unsigned int h = f2bf(v1);
        *(unsigned short*)(smem + L_W1T + byte) = (unsigned short)h;
        *(unsigned short*)(smem + L_W1T + PLANE + byte) =
            (unsigned short)f2bf(v1 - __uint_as_float(h << 16));
        float v2 = W2[j * 64 + i];
        h = f2bf(v2);
        *(unsigned short*)(smem + L_W2T + byte) = (unsigned short)h;
        *(unsigned short*)(smem + L_W2T + PLANE + byte) =
            (unsigned short)f2bf(v2 - __uint_as_float(h << 16));
    }
    // ---- stage G planes from ws (already split; apply swizzle) ----
    for (int c = tid; c < 1024; c += 256) {
        uint4 v = *(const uint4*)(ws + WS_G + c * 16);
        int pc = c & 511, p = c >> 9;
        int row = pc >> 3;
        int byte = (pc * 16) ^ ((row & 7) << 4);
        *(uint4*)(smem + L_G + p * 8192 + byte) = v;
    }
    float b1v[4], b2v[4];
#pragma unroll
    for (int nt = 0; nt < 4; ++nt) {
        b1v[nt] = b1[(lane & 15) + nt * 16];
        b2v[nt] = b2[(lane & 15) + nt * 16];
    }
    __syncthreads();   // barrier 0: weights staged

    char* X = smem + L_XY + w * 8192;
    char* Y = X + 4096;

    // ================= key tile (wave w owns keys 16w..16w+15) =================
    f32x4 zacc[4];
    {
        float x[48];
        pe48(x, input_poses + ((size_t)s * 64 + 16 * w + (lane & 15)) * 16);
        writeA(X, x, lane);

        f32x4 acc[4];
#pragma unroll
        for (int nt = 0; nt < 4; ++nt) acc[nt] = mk4(b1v[nt]);
        gemm16(X, TPLANE, smem + L_W1T, PLANE, acc, lane);   // L1
        store_c(Y, Y + TPLANE, acc, 0, lane, true);          // H1 -> Y
#pragma unroll
        for (int nt = 0; nt < 4; ++nt) acc[nt] = mk4(b2v[nt]);
        gemm16(Y, TPLANE, smem + L_W2T, PLANE, acc, lane);   // L2
        store_c(X, X + TPLANE, acc, 0, lane, true);          // H2k -> X

        // ck[k] = g . h2k   (lane: key=lane&15, j-quarter=lane>>4)
        {
            int r = lane & 15;
            int bA = lds_addr(r, (lane >> 4) * 32);
            int bB = lds_addr(r, (lane >> 4) * 32 + 16);
            short8 h0 = *(const short8*)(X + bA);
            short8 h1 = *(const short8*)(X + bB);
            short8 l0 = *(const short8*)(X + TPLANE + bA);
            short8 l1 = *(const short8*)(X + TPLANE + bB);
            const float4* gp = (const float4*)((const char*)ws + WS_g) + (lane >> 4) * 4;
            float4 g0 = gp[0], g1 = gp[1], g2 = gp[2], g3 = gp[3];
            float gv[16] = {g0.x, g0.y, g0.z, g0.w, g1.x, g1.y, g1.z, g1.w,
                            g2.x, g2.y, g2.z, g2.w, g3.x, g3.y, g3.z, g3.w};
            float ckp = 0.f;
#pragma unroll
            for (int e = 0; e < 8; ++e) {
                ckp = fmaf(bf2f(h0[e]) + bf2f(l0[e]), gv[e], ckp);
                ckp = fmaf(bf2f(h1[e]) + bf2f(l1[e]), gv[8 + e], ckp);
            }
            ckp += __shfl_xor(ckp, 16);
            ckp += __shfl_xor(ckp, 32);
            if (lane < 16) *(float*)(Y + lane * 4) = ckp;   // stash ck slice in own Y
        }

        // ZkT tile = H2k @ G (symmetric): rows=key, cols=j  (held in regs)
#pragma unroll
        for (int nt = 0; nt < 4; ++nt) zacc[nt] = mk4(0.f);
        gemm16(X, TPLANE, smem + L_G, PLANE, zacc, lane);
    }
    __syncthreads();   // barrier 1: all G reads & ck writes done
    store_c(smem + L_G, smem + L_G + PLANE, zacc, 16 * w, lane, false);  // ZkT over G
    float ckreg[4];
#pragma unroll
    for (int nt = 0; nt < 4; ++nt)
        ckreg[nt] = *(const float*)(smem + L_XY + nt * 8192 + 4096 + (lane & 15) * 4);
    __syncthreads();   // barrier 2: ZkT visible; ck cached; Y free

    // ================= query tiles (4 per wave, barrier-free) =================
    float* outS = out + (size_t)s * 16384;
#pragma unroll 1
    for (int it = 0; it < 4; ++it) {
        const int qbase = (it * 4 + w) * 16;
        float x[48];
        pe48(x, target_poses + ((size_t)s * 256 + qbase + (lane & 15)) * 16);
        writeA(X, x, lane);

        f32x4 acc[4];
#pragma unroll
        for (int nt = 0; nt < 4; ++nt) acc[nt] = mk4(b1v[nt]);
        gemm16(X, TPLANE, smem + L_W1T, PLANE, acc, lane);   // L1
        store_c(Y, Y + TPLANE, acc, 0, lane, true);
#pragma unroll
        for (int nt = 0; nt < 4; ++nt) acc[nt] = mk4(b2v[nt]);
        gemm16(Y, TPLANE, smem + L_W2T, PLANE, acc, lane);   // L2
        store_c(X, X + TPLANE, acc, 0, lane, true);
#pragma unroll
        for (int nt = 0; nt < 4; ++nt) acc[nt] = mk4(ckreg[nt]);   // +ck via C-init
        gemm16(X, TPLANE, smem + L_G, PLANE, acc, lane);     // scores (B = ZkT)

        // softmax over 64 k: lane-local over nt, then xor 1/2/4/8 across 16 lanes
#pragma unroll
        for (int r = 0; r < 4; ++r) {
            float m = fmaxf(fmaxf(acc[0][r], acc[1][r]), fmaxf(acc[2][r], acc[3][r]));
            m = fmaxf(m, __shfl_xor(m, 1));
            m = fmaxf(m, __shfl_xor(m, 2));
            m = fmaxf(m, __shfl_xor(m, 4));
            m = fmaxf(m, __shfl_xor(m, 8));
            float e0 = __expf((acc[0][r] - m) * SCALE);
            float e1 = __expf((acc[1][r] - m) * SCALE);
            float e2 = __expf((acc[2][r] - m) * SCALE);
            float e3 = __expf((acc[3][r] - m) * SCALE);
            float ssum = e0 + e1 + e2 + e3;
            ssum += __shfl_xor(ssum, 1);
            ssum += __shfl_xor(ssum, 2);
            ssum += __shfl_xor(ssum, 4);
            ssum += __shfl_xor(ssum, 8);
            float iv = 1.f / ssum;
            acc[0][r] = e0 * iv; acc[1][r] = e1 * iv;
            acc[2][r] = e2 * iv; acc[3][r] = e3 * iv;
        }
        // transposed store out[s][k][q]: float4 over 4 consecutive q (C rows)
        int qoff = qbase + ((lane >> 4) << 2);
#pragma unroll
        for (int nt = 0; nt < 4; ++nt) {
            int k = (lane & 15) + nt * 16;
            *(float4*)(outS + k * 256 + qoff) =
                make_float4(acc[nt][0], acc[nt][1], acc[nt][2], acc[nt][3]);
        }
    }
}

extern "C" void kernel_launch(void* const* d_in, const int* in_sizes, int n_in,
                              void* d_out, int out_size, void* d_ws, size_t ws_size,
                              hipStream_t stream) {
    const float* input_poses  = (const float*)d_in[0];
    const float* target_poses = (const float*)d_in[1];
    const float* W1 = (const float*)d_in[2];
    const float* b1 = (const float*)d_in[3];
    const float* W2 = (const float*)d_in[4];
    const float* b2 = (const float*)d_in[5];
    const float* W3 = (const float*)d_in[6];
    const float* b3 = (const float*)d_in[7];
    float* out = (float*)d_out;
    char* ws = (char*)d_ws;   // uses 16640 bytes

    precompute_kernel<<<dim3(1), dim3(256), 0, stream>>>(W3, b3, ws);
    cam_mfma_kernel<<<dim3(1024), dim3(256), 0, stream>>>(
        input_poses, target_poses, W1, b1, W2, b2, ws, out);
}

// Round 6
// 79.344 us; speedup vs baseline: 22.8388x; 1.2152x over previous
//
#include <hip/hip_runtime.h>
#include <math.h>

typedef __attribute__((ext_vector_type(8))) short short8;
typedef __attribute__((ext_vector_type(4))) float f32x4;

#define SCALE 0.08838834764831845f   // 1/sqrt(128)

// d_ws byte offsets
#define WS_G 0        // G planes: hi [64][64]bf16 (8192 B), lo (+8192)
#define WS_g 16384    // g = W3 b3, 64 f32

// LDS byte offsets (81920 B total -> 2 blocks/CU)
#define L_W1T 0       // [64 i][64 j] bf16 hi, lo at +8192 (cols 42..63 zero)
#define L_W2T 16384
#define L_G   32768   // G planes; overwritten by ZkT after barrier 1
#define L_XY  49152   // per-wave X/Y tile planes: wave w at +w*8192
#define PLANE 8192    // lo-offset for big [64]-row planes
#define TPLANE 2048   // lo-offset for [16]-row tile planes

__device__ __forceinline__ unsigned int f2bf(float f) {   // RNE (precompute only)
    unsigned int u = __float_as_uint(f);
    return (u + 0x7fffu + ((u >> 16) & 1u)) >> 16;
}
__device__ __forceinline__ f32x4 mk4(float v) { f32x4 r = {v, v, v, v}; return r; }

// truncation split: hi = top 16 bits, lo = trunc(v - hi)
__device__ __forceinline__ void splitw(char* hi, int loOff, int addr, float v) {
    unsigned u = __float_as_uint(v);
    *(unsigned short*)(hi + addr) = (unsigned short)(u >> 16);
    float res = v - __uint_as_float(u & 0xffff0000u);
    *(unsigned short*)(hi + loOff + addr) = (unsigned short)(__float_as_uint(res) >> 16);
}

// ---- per-quarter PE: seed sincos at this quarter's start freq, <=2 doublings ----
// features: [loc3 | per freq i: sin(3), cos(3), f_i = 1.5*2^i, i=0..5 | dir3 | pad0]
__device__ __forceinline__ void pe_values(float* v, const float* __restrict__ pose, int qt) {
    float2 r0 = *(const float2*)(pose + 2);
    float2 r1 = *(const float2*)(pose + 6);
    float2 r2 = *(const float2*)(pose + 10);
    const float L[3] = {r0.y, r1.y, r2.y};
    const float sc = (qt == 0) ? 1.5f : ((qt == 1) ? 6.f : 24.f);
    float s0[3], c0[3], s1[3], c1[3], s2[3], c2[3];
#pragma unroll
    for (int c = 0; c < 3; ++c) {
        __sincosf(sc * L[c], &s0[c], &c0[c]);
        s1[c] = 2.f * s0[c] * c0[c];
        c1[c] = fmaf(c0[c], c0[c], -s0[c] * s0[c]);
        s2[c] = 2.f * s1[c] * c1[c];
        c2[c] = fmaf(c1[c], c1[c], -s1[c] * s1[c]);
    }
    if (qt == 0) {          // feats 0..15: loc, s0,c0, s1,c1, s2x   (seed=f0)
        v[0]=L[0]; v[1]=L[1]; v[2]=L[2];
        v[3]=s0[0]; v[4]=s0[1]; v[5]=s0[2];
        v[6]=c0[0]; v[7]=c0[1]; v[8]=c0[2];
        v[9]=s1[0]; v[10]=s1[1]; v[11]=s1[2];
        v[12]=c1[0]; v[13]=c1[1]; v[14]=c1[2];
        v[15]=s2[0];
    } else if (qt == 1) {   // feats 16..31: s2yz, c2, s3, c3, s4, c4xy (seed=f2)
        v[0]=s0[1]; v[1]=s0[2];
        v[2]=c0[0]; v[3]=c0[1]; v[4]=c0[2];
        v[5]=s1[0]; v[6]=s1[1]; v[7]=s1[2];
        v[8]=c1[0]; v[9]=c1[1]; v[10]=c1[2];
        v[11]=s2[0]; v[12]=s2[1]; v[13]=s2[2];
        v[14]=c2[0]; v[15]=c2[1];
    } else if (qt == 2) {   // feats 32..47: c4z, s5, c5, dirs, 0x6 (seed=f4)
        v[0]=c0[2];
        v[1]=s1[0]; v[2]=s1[1]; v[3]=s1[2];
        v[4]=c1[0]; v[5]=c1[1]; v[6]=c1[2];
        v[7]=r0.x; v[8]=r1.x; v[9]=r2.x;
        v[10]=0.f; v[11]=0.f; v[12]=0.f; v[13]=0.f; v[14]=0.f; v[15]=0.f;
    } else {                // feats 48..63: zeros
#pragma unroll
        for (int t = 0; t < 16; ++t) v[t] = 0.f;
    }
}

// pack v[16] -> hi/lo bf16, write 2x uint4 per plane at this lane's quarter
__device__ __forceinline__ void writeA16(char* X, int l15, int swzA, int qt, const float* v) {
    unsigned h[8], l[8];
#pragma unroll
    for (int p = 0; p < 8; ++p) {
        float a = v[2 * p], b = v[2 * p + 1];
        unsigned ua = __float_as_uint(a), ub = __float_as_uint(b);
        h[p] = (ub & 0xffff0000u) | (ua >> 16);
        float ra = a - __uint_as_float(ua & 0xffff0000u);
        float rb = b - __uint_as_float(ub & 0xffff0000u);
        l[p] = (__float_as_uint(rb) & 0xffff0000u) | (__float_as_uint(ra) >> 16);
    }
    const int cb = qt * 32;
    const int a1 = l15 * 128 + (cb ^ swzA);
    const int a2 = l15 * 128 + ((cb + 16) ^ swzA);
    *(uint4*)(X + a1) = make_uint4(h[0], h[1], h[2], h[3]);
    *(uint4*)(X + a2) = make_uint4(h[4], h[5], h[6], h[7]);
    *(uint4*)(X + TPLANE + a1) = make_uint4(l[0], l[1], l[2], l[3]);
    *(uint4*)(X + TPLANE + a2) = make_uint4(l[4], l[5], l[6], l[7]);
}

// C tile -> hi/lo planes (no relu; caller relus acc in place)
__device__ __forceinline__ void store_c16(char* hi, int loOff, const f32x4* acc,
                                          int rowbase, int lane) {
    const int l15 = lane & 15, q4 = (lane >> 4) << 2;
#pragma unroll
    for (int r = 0; r < 4; ++r) {
        const int row = rowbase + q4 + r;
        const int rterm = row * 128, swz = (row & 7) << 4;
#pragma unroll
        for (int nt = 0; nt < 4; ++nt) {
            splitw(hi, loOff, rterm + ((l15 * 2 + nt * 32) ^ swz), acc[nt][r]);
        }
    }
}

// C += A*B over K=64, hi/lo split (hh+hl+lh), B from LDS
__device__ __forceinline__ void gemm16_ldsB(const char* A, const char* B, int bloOff,
                                            int aoff0, int aoff1, f32x4* acc) {
    short8 Ah0 = *(const short8*)(A + aoff0);
    short8 Ah1 = *(const short8*)(A + aoff1);
    short8 Al0 = *(const short8*)(A + aoff0 + TPLANE);
    short8 Al1 = *(const short8*)(A + aoff1 + TPLANE);
#pragma unroll
    for (int nt = 0; nt < 4; ++nt) {
        const char* b = B + nt * 2048;
        short8 bh0 = *(const short8*)(b + aoff0);
        short8 bl0 = *(const short8*)(b + aoff0 + bloOff);
        short8 bh1 = *(const short8*)(b + aoff1);
        short8 bl1 = *(const short8*)(b + aoff1 + bloOff);
        f32x4 a = acc[nt];
        a = __builtin_amdgcn_mfma_f32_16x16x32_bf16(Ah0, bh0, a, 0, 0, 0);
        a = __builtin_amdgcn_mfma_f32_16x16x32_bf16(Ah0, bl0, a, 0, 0, 0);
        a = __builtin_amdgcn_mfma_f32_16x16x32_bf16(Al0, bh0, a, 0, 0, 0);
        a = __builtin_amdgcn_mfma_f32_16x16x32_bf16(Ah1, bh1, a, 0, 0, 0);
        a = __builtin_amdgcn_mfma_f32_16x16x32_bf16(Ah1, bl1, a, 0, 0, 0);
        a = __builtin_amdgcn_mfma_f32_16x16x32_bf16(Al1, bh1, a, 0, 0, 0);
        acc[nt] = a;
    }
}

// same but B fragments live in registers (W2T)
__device__ __forceinline__ void gemm16_regB(const char* A, const short8 (&B)[2][4][2],
                                            int aoff0, int aoff1, f32x4* acc) {
    short8 Ah0 = *(const short8*)(A + aoff0);
    short8 Ah1 = *(const short8*)(A + aoff1);
    short8 Al0 = *(const short8*)(A + aoff0 + TPLANE);
    short8 Al1 = *(const short8*)(A + aoff1 + TPLANE);
#pragma unroll
    for (int nt = 0; nt < 4; ++nt) {
        f32x4 a = acc[nt];
        a = __builtin_amdgcn_mfma_f32_16x16x32_bf16(Ah0, B[0][nt][0], a, 0, 0, 0);
        a = __builtin_amdgcn_mfma_f32_16x16x32_bf16(Ah0, B[0][nt][1], a, 0, 0, 0);
        a = __builtin_amdgcn_mfma_f32_16x16x32_bf16(Al0, B[0][nt][0], a, 0, 0, 0);
        a = __builtin_amdgcn_mfma_f32_16x16x32_bf16(Ah1, B[1][nt][0], a, 0, 0, 0);
        a = __builtin_amdgcn_mfma_f32_16x16x32_bf16(Ah1, B[1][nt][1], a, 0, 0, 0);
        a = __builtin_amdgcn_mfma_f32_16x16x32_bf16(Al1, B[1][nt][0], a, 0, 0, 0);
        acc[nt] = a;
    }
}

#define RELU4(ACC) do {                                                  \
    _Pragma("unroll")                                                    \
    for (int _n = 0; _n < 4; ++_n) {                                     \
        _Pragma("unroll")                                                \
        for (int _r = 0; _r < 4; ++_r)                                   \
            (ACC)[_n][_r] = fmaxf((ACC)[_n][_r], 0.f);                   \
    }                                                                    \
} while (0)

// ---------------- kernel 1: G = W3 W3^T (bf16 hi/lo), g = W3 b3 ----------------
__global__ __launch_bounds__(256) void precompute_kernel(
    const float* __restrict__ W3, const float* __restrict__ b3, char* __restrict__ ws)
{
    __shared__ float W3t[128][64];
    const int tid = threadIdx.x;
    for (int e = tid; e < 8192; e += 256) W3t[e & 127][e >> 7] = W3[e];
    __syncthreads();

    unsigned short* gh = (unsigned short*)(ws + WS_G);
    unsigned short* gl = gh + 4096;
    for (int idx = tid; idx < 4096; idx += 256) {
        int r = idx >> 6, k = idx & 63;
        float a = 0.f;
        for (int d = 0; d < 128; ++d) a = fmaf(W3t[d][r], W3t[d][k], a);
        unsigned int h = f2bf(a);
        gh[idx] = (unsigned short)h;
        gl[idx] = (unsigned short)f2bf(a - __uint_as_float(h << 16));
    }
    if (tid < 64) {
        float a = 0.f;
        for (int d = 0; d < 128; ++d) a = fmaf(W3t[d][tid], b3[d], a);
        ((float*)(ws + WS_g))[tid] = a;
    }
}

// ---------------- kernel 2: fused MFMA kernel, 1 scene/block ----------------
__global__ __launch_bounds__(256, 2) void cam_mfma_kernel(
    const float* __restrict__ input_poses, const float* __restrict__ target_poses,
    const float* __restrict__ W1, const float* __restrict__ b1,
    const float* __restrict__ W2, const float* __restrict__ b2,
    const char* __restrict__ ws, float* __restrict__ out)
{
    __shared__ __align__(16) char smem[81920];
    const int tid = threadIdx.x, lane = tid & 63, w = tid >> 6, s = blockIdx.x;
    const int l15 = lane & 15;
    const int qt = lane >> 4, q4 = qt << 2;
    const int swzA = (l15 & 7) << 4;
    const int aoff0 = l15 * 128 + ((qt << 4) ^ swzA);          // ks=0 frag offset
    const int aoff1 = l15 * 128 + ((64 + (qt << 4)) ^ swzA);   // ks=1 frag offset

    // ---- stage W1T/W2T (truncation split, swizzled) ----
    for (int idx = tid; idx < 4096; idx += 256) {
        int i = idx & 63, j = idx >> 6;              // coalesced over i
        int a = i * 128 + ((j * 2) ^ ((i & 7) << 4));
        float v1 = (j < 42) ? W1[j * 64 + i] : 0.f;
        splitw(smem + L_W1T, PLANE, a, v1);
        splitw(smem + L_W2T, PLANE, a, W2[j * 64 + i]);
    }
    // ---- stage G planes from ws (pre-split; apply swizzle) ----
    for (int c = tid; c < 1024; c += 256) {
        uint4 v4 = *(const uint4*)(ws + WS_G + c * 16);
        int pc = c & 511, p = c >> 9, row = pc >> 3;
        *(uint4*)(smem + L_G + p * 8192 + ((pc * 16) ^ ((row & 7) << 4))) = v4;
    }
    float b1v[4], b2v[4], gv[4];
#pragma unroll
    for (int nt = 0; nt < 4; ++nt) {
        b1v[nt] = b1[l15 + nt * 16];
        b2v[nt] = b2[l15 + nt * 16];
        gv[nt]  = ((const float*)(ws + WS_g))[l15 + nt * 16];
    }
    __syncthreads();   // barrier 0

    // W2T fragments -> registers (reused by all 5 tiles)
    short8 w2r[2][4][2];
#pragma unroll
    for (int ks = 0; ks < 2; ++ks)
#pragma unroll
        for (int nt = 0; nt < 4; ++nt) {
            const char* b = smem + L_W2T + nt * 2048 + (ks ? aoff1 : aoff0);
            w2r[ks][nt][0] = *(const short8*)(b);
            w2r[ks][nt][1] = *(const short8*)(b + PLANE);
        }

    char* X = smem + L_XY + w * 8192;
    char* Y = X + 4096;
    float v[16];

    // ================= key tile (wave w owns keys 16w..16w+15) =================
    {
        pe_values(v, input_poses + ((size_t)s * 64 + 16 * w + l15) * 16, qt);
        writeA16(X, l15, swzA, qt, v);

        f32x4 acc[4];
#pragma unroll
        for (int nt = 0; nt < 4; ++nt) acc[nt] = mk4(b1v[nt]);
        gemm16_ldsB(X, smem + L_W1T, PLANE, aoff0, aoff1, acc);       // L1
        RELU4(acc);
        store_c16(Y, TPLANE, acc, 0, lane);                            // H1 -> Y
#pragma unroll
        for (int nt = 0; nt < 4; ++nt) acc[nt] = mk4(b2v[nt]);
        gemm16_regB(Y, w2r, aoff0, aoff1, acc);                        // L2
        RELU4(acc);
        store_c16(X, TPLANE, acc, 0, lane);                            // H2k -> X

        // ck[k] = g . h2k  from registers: reduce over hidden (lanes l15 + nt)
#pragma unroll
        for (int r = 0; r < 4; ++r) {
            float t = acc[0][r] * gv[0];
            t = fmaf(acc[1][r], gv[1], t);
            t = fmaf(acc[2][r], gv[2], t);
            t = fmaf(acc[3][r], gv[3], t);
            t += __shfl_xor(t, 1);
            t += __shfl_xor(t, 2);
            t += __shfl_xor(t, 4);
            t += __shfl_xor(t, 8);
            if (l15 == 0) *(float*)(Y + (q4 + r) * 4) = t;   // stash ck in own Y
        }

        // ZkT tile = H2k @ G (symmetric)
        f32x4 zacc[4];
#pragma unroll
        for (int nt = 0; nt < 4; ++nt) zacc[nt] = mk4(0.f);
        gemm16_ldsB(X, smem + L_G, PLANE, aoff0, aoff1, zacc);

        // prefetch PE of query tile 0 (VALU only, fills barrier shadow)
        pe_values(v, target_poses + ((size_t)s * 256 + w * 16 + l15) * 16, qt);

        __syncthreads();   // barrier 1: all G reads & ck writes done
        store_c16(smem + L_G, PLANE, zacc, 16 * w, lane);              // ZkT over G
    }
    float ckreg[4];
#pragma unroll
    for (int nt = 0; nt < 4; ++nt)
        ckreg[nt] = *(const float*)(smem + L_XY + nt * 8192 + 4096 + l15 * 4);
    __syncthreads();   // barrier 2: ZkT visible; ck cached

    // ================= query tiles (4 per wave, pipelined) =================
    writeA16(X, l15, swzA, qt, v);    // tile 0 PE
    float* outS = out + (size_t)s * 16384;
#pragma unroll 1
    for (int it = 0; it < 4; ++it) {
        f32x4 acc[4];
#pragma unroll
        for (int nt = 0; nt < 4; ++nt) acc[nt] = mk4(b1v[nt]);
        gemm16_ldsB(X, smem + L_W1T, PLANE, aoff0, aoff1, acc);        // L1
        RELU4(acc);
        store_c16(Y, TPLANE, acc, 0, lane);
#pragma unroll
        for (int nt = 0; nt < 4; ++nt) acc[nt] = mk4(b2v[nt]);
        gemm16_regB(Y, w2r, aoff0, aoff1, acc);                        // L2
        RELU4(acc);
        store_c16(X, TPLANE, acc, 0, lane);
#pragma unroll
        for (int nt = 0; nt < 4; ++nt) acc[nt] = mk4(ckreg[nt]);       // +ck init
        gemm16_ldsB(X, smem + L_G, PLANE, aoff0, aoff1, acc);          // scores

        // PE + A-write for next tile: issued under the score-MFMA shadow.
        // WAR on X is safe: same-wave DS ops execute in order (R5 precedent).
        if (it < 3) {
            pe_values(v, target_poses +
                      ((size_t)s * 256 + ((it + 1) * 4 + w) * 16 + l15) * 16, qt);
            writeA16(X, l15, swzA, qt, v);
        }

        // softmax over 64 k: over nt locally, then xor 1/2/4/8 across 16 lanes
#pragma unroll
        for (int r = 0; r < 4; ++r) {
            float m = fmaxf(fmaxf(acc[0][r], acc[1][r]), fmaxf(acc[2][r], acc[3][r]));
            m = fmaxf(m, __shfl_xor(m, 1));
            m = fmaxf(m, __shfl_xor(m, 2));
            m = fmaxf(m, __shfl_xor(m, 4));
            m = fmaxf(m, __shfl_xor(m, 8));
            float e0 = __expf((acc[0][r] - m) * SCALE);
            float e1 = __expf((acc[1][r] - m) * SCALE);
            float e2 = __expf((acc[2][r] - m) * SCALE);
            float e3 = __expf((acc[3][r] - m) * SCALE);
            float ssum = e0 + e1 + e2 + e3;
            ssum += __shfl_xor(ssum, 1);
            ssum += __shfl_xor(ssum, 2);
            ssum += __shfl_xor(ssum, 4);
            ssum += __shfl_xor(ssum, 8);
            float iv = 1.f / ssum;
            acc[0][r] = e0 * iv; acc[1][r] = e1 * iv;
            acc[2][r] = e2 * iv; acc[3][r] = e3 * iv;
        }
        // transposed store out[s][k][q]: float4 over 4 consecutive q
        const int qoff = (it * 4 + w) * 16 + q4;
#pragma unroll
        for (int nt = 0; nt < 4; ++nt) {
            int k = l15 + 16 * nt;
            *(float4*)(outS + (size_t)k * 256 + qoff) =
                make_float4(acc[nt][0], acc[nt][1], acc[nt][2], acc[nt][3]);
        }
    }
}

extern "C" void kernel_launch(void* const* d_in, const int* in_sizes, int n_in,
                              void* d_out, int out_size, void* d_ws, size_t ws_size,
                              hipStream_t stream) {
    const float* input_poses  = (const float*)d_in[0];
    const float* target_poses = (const float*)d_in[1];
    const float* W1 = (const float*)d_in[2];
    const float* b1 = (const float*)d_in[3];
    const float* W2 = (const float*)d_in[4];
    const float* b2 = (const float*)d_in[5];
    const float* W3 = (const float*)d_in[6];
    const float* b3 = (const float*)d_in[7];
    float* out = (float*)d_out;
    char* ws = (char*)d_ws;   // uses 16640 bytes

    precompute_kernel<<<dim3(1), dim3(256), 0, stream>>>(W3, b3, ws);
    cam_mfma_kernel<<<dim3(1024), dim3(256), 0, stream>>>(
        input_poses, target_poses, W1, b1, W2, b2, ws, out);
}